// Round 1
// baseline (305.642 us; speedup 1.0000x reference)
//
#include <hip/hip_runtime.h>
#include <stdint.h>

// ---------------------------------------------------------------------------
// SelfAttention: QKV proj (fp32 -> bf16 MFMA GEMM) + causal flash attention.
// B=8, S=2048, D=256. out fp32 [B,S,D].
// ws layout: Qb bf16 [B][S][D] (pre-scaled 1/16), Kb bf16 [B][S][D],
//            Vt bf16 [B][D][S] (transposed for PV B-operand).
// ---------------------------------------------------------------------------

typedef __attribute__((ext_vector_type(8))) short bf16x8;
typedef __attribute__((ext_vector_type(4))) float f32x4;

#define NEGF -3.0e38f
#define LDP  40   // padded LDS row stride (bf16 elems): 80B rows -> 16B-aligned b128, 2-way banks

__device__ __forceinline__ unsigned short f2bf(float f){
  union { float f; unsigned u; } v; v.f = f;
  unsigned r = v.u + 0x7FFFu + ((v.u >> 16) & 1u);   // RNE
  return (unsigned short)(r >> 16);
}
__device__ __forceinline__ unsigned pk2(float a, float b){
  return (unsigned)f2bf(a) | ((unsigned)f2bf(b) << 16);
}

// ---------------------------------------------------------------------------
// Kernel 1: QKV projection. C[m,n] = sum_k E[m,k] * W[n,k]  (NT GEMM).
// Grid (6, 128): x = n-tile (0,1->WQ; 2,3->WK; 4,5->WV), y = m-tile (128 rows).
// ---------------------------------------------------------------------------
__global__ __launch_bounds__(256) void qkv_proj_kernel(
    const float* __restrict__ E, const float* __restrict__ WQ,
    const float* __restrict__ WK, const float* __restrict__ WV,
    unsigned short* __restrict__ Qb, unsigned short* __restrict__ Kb,
    unsigned short* __restrict__ Vt)
{
  __shared__ unsigned short As[128*LDP];
  __shared__ unsigned short Bs[128*LDP];
  const int tn = blockIdx.x;
  const int tm = blockIdx.y;
  const int m0 = tm * 128;
  const int widx = tn >> 1;                 // 0=Q 1=K 2=V
  const float* Wp = (widx==0) ? WQ : ((widx==1) ? WK : WV);
  const int nw0 = (tn & 1) * 128;           // row offset within weight

  const int t = threadIdx.x;
  const int lane = t & 63, wid = t >> 6;
  const int hi = lane >> 4, lo = lane & 15;
  const int wm = wid >> 1, wn = wid & 1;    // 2x2 wave grid, 64x64 each

  const int srow = t >> 1;                  // staging: 2 threads per row
  const int scg  = (t & 1) * 16;            // 16 floats each

  const f32x4 fzero = {0.f, 0.f, 0.f, 0.f};
  f32x4 acc[4][4];
#pragma unroll
  for (int i=0;i<4;i++)
#pragma unroll
    for (int j=0;j<4;j++) acc[i][j] = fzero;

  for (int kk = 0; kk < 256; kk += 32) {
    const float* ga = E  + (size_t)(m0  + srow)*256 + kk + scg;
    const float* gb = Wp + (size_t)(nw0 + srow)*256 + kk + scg;
    float4 va0 = *reinterpret_cast<const float4*>(ga);
    float4 va1 = *reinterpret_cast<const float4*>(ga+4);
    float4 va2 = *reinterpret_cast<const float4*>(ga+8);
    float4 va3 = *reinterpret_cast<const float4*>(ga+12);
    float4 vb0 = *reinterpret_cast<const float4*>(gb);
    float4 vb1 = *reinterpret_cast<const float4*>(gb+4);
    float4 vb2 = *reinterpret_cast<const float4*>(gb+8);
    float4 vb3 = *reinterpret_cast<const float4*>(gb+12);
    __syncthreads();   // previous iter's LDS reads done
    uint4 wv;
    wv.x = pk2(va0.x, va0.y); wv.y = pk2(va0.z, va0.w);
    wv.z = pk2(va1.x, va1.y); wv.w = pk2(va1.z, va1.w);
    *reinterpret_cast<uint4*>(&As[srow*LDP + scg]) = wv;
    wv.x = pk2(va2.x, va2.y); wv.y = pk2(va2.z, va2.w);
    wv.z = pk2(va3.x, va3.y); wv.w = pk2(va3.z, va3.w);
    *reinterpret_cast<uint4*>(&As[srow*LDP + scg + 8]) = wv;
    wv.x = pk2(vb0.x, vb0.y); wv.y = pk2(vb0.z, vb0.w);
    wv.z = pk2(vb1.x, vb1.y); wv.w = pk2(vb1.z, vb1.w);
    *reinterpret_cast<uint4*>(&Bs[srow*LDP + scg]) = wv;
    wv.x = pk2(vb2.x, vb2.y); wv.y = pk2(vb2.z, vb2.w);
    wv.z = pk2(vb3.x, vb3.y); wv.w = pk2(vb3.z, vb3.w);
    *reinterpret_cast<uint4*>(&Bs[srow*LDP + scg + 8]) = wv;
    __syncthreads();

    bf16x8 af[4], bfr[4];
#pragma unroll
    for (int f=0; f<4; f++){
      af[f]  = *reinterpret_cast<const bf16x8*>(&As[(wm*64 + f*16 + lo)*LDP + 8*hi]);
      bfr[f] = *reinterpret_cast<const bf16x8*>(&Bs[(wn*64 + f*16 + lo)*LDP + 8*hi]);
    }
#pragma unroll
    for (int i=0;i<4;i++)
#pragma unroll
      for (int j=0;j<4;j++)
        acc[i][j] = __builtin_amdgcn_mfma_f32_16x16x32_bf16(af[i], bfr[j], acc[i][j], 0,0,0);
  }

  // Epilogue. C/D layout: row = (lane>>4)*4 + reg, col = lane&15.
  const int b  = m0 >> 11;
  const int s0 = m0 & 2047;
  if (widx < 2) {
    unsigned short* Out = (widx==0) ? Qb : Kb;
    const float mul = (widx==0) ? 0.0625f : 1.0f;   // fold 1/sqrt(D) into Q (exact pow2)
#pragma unroll
    for (int i=0;i<4;i++){
      const int mrow = m0 + wm*64 + i*16 + hi*4;
#pragma unroll
      for (int j=0;j<4;j++){
        const int col = nw0 + wn*64 + j*16 + lo;
#pragma unroll
        for (int r=0;r<4;r++)
          Out[(size_t)(mrow + r)*256 + col] = f2bf(acc[i][j][r]*mul);
      }
    }
  } else {
    // V stored transposed: Vt[b][d][s]
#pragma unroll
    for (int i=0;i<4;i++){
      const int sr = s0 + wm*64 + i*16 + hi*4;
#pragma unroll
      for (int j=0;j<4;j++){
        const int d = nw0 + wn*64 + j*16 + lo;
        unsigned short* vp = Vt + ((size_t)b*256 + d)*2048 + sr;
#pragma unroll
        for (int r=0;r<4;r++) vp[r] = f2bf(acc[i][j][r]);
      }
    }
  }
}

// ---------------------------------------------------------------------------
// Kernel 2: causal flash attention. 256 blocks, 4 independent waves/block,
// 16 q-rows per wave (64/block), kv-tiles of 32. batch = bid&7 -> XCD-pinned
// K/V (2MB/batch fits one XCD's 4MB L2).
// ---------------------------------------------------------------------------
__global__ __launch_bounds__(256) void attn_kernel(
    const unsigned short* __restrict__ Qb, const unsigned short* __restrict__ Kb,
    const unsigned short* __restrict__ Vt, float* __restrict__ Out)
{
  __shared__ unsigned short Pl[4][16*LDP];  // per-wave P transpose buffer
  const int bid = blockIdx.x;
  const int b    = bid & 7;
  const int tile = bid >> 3;                // 0..31
  const int t = threadIdx.x;
  const int lane = t & 63, w = t >> 6;
  const int hi = lane >> 4, lo = lane & 15;
  const int qw0 = tile*64 + w*16;           // this wave's first q row

  // Q fragments in registers for the whole kernel (A-op: row=lo, k=8*hi+j)
  const unsigned short* Qp = Qb + ((size_t)(b*2048 + qw0 + lo))*256 + 8*hi;
  bf16x8 qf[8];
#pragma unroll
  for (int kc=0;kc<8;kc++) qf[kc] = *reinterpret_cast<const bf16x8*>(Qp + kc*32);

  const f32x4 fzero = {0.f, 0.f, 0.f, 0.f};
  f32x4 accO[16];
#pragma unroll
  for (int i=0;i<16;i++) accO[i] = fzero;
  float m_r[4] = {NEGF,NEGF,NEGF,NEGF};
  float l_r[4] = {0.f,0.f,0.f,0.f};

  const unsigned short* Kbase = Kb + (size_t)b*2048*256;
  const unsigned short* Vbase = Vt + (size_t)b*256*2048 + (size_t)lo*2048 + 8*hi;
  unsigned short* Pw = Pl[w];
  const int nkv = (qw0 + 47) >> 5;          // kv tiles covering rows 0..qw0+15

  for (int it = 0; it < nkv; ++it){
    const int kv0 = it*32;
    // S-tile = Q * K^T (scale pre-folded into Q)
    f32x4 s0v = fzero, s1v = fzero;
    const unsigned short* Kp = Kbase + (size_t)(kv0 + lo)*256 + 8*hi;
#pragma unroll
    for (int kc=0;kc<8;kc++){
      bf16x8 k0 = *reinterpret_cast<const bf16x8*>(Kp + kc*32);
      bf16x8 k1 = *reinterpret_cast<const bf16x8*>(Kp + 16*256 + kc*32);
      s0v = __builtin_amdgcn_mfma_f32_16x16x32_bf16(qf[kc], k0, s0v, 0,0,0);
      s1v = __builtin_amdgcn_mfma_f32_16x16x32_bf16(qf[kc], k1, s1v, 0,0,0);
    }
    const bool need_mask = (kv0 + 31) > qw0;
    float alpha[4];
#pragma unroll
    for (int r=0;r<4;r++){
      float v0 = s0v[r], v1 = s1v[r];
      if (need_mask){
        const int q = qw0 + hi*4 + r;
        if (kv0 + lo      > q) v0 = NEGF;
        if (kv0 + 16 + lo > q) v1 = NEGF;
      }
      float mx = fmaxf(v0, v1);
#pragma unroll
      for (int sh=1; sh<16; sh<<=1) mx = fmaxf(mx, __shfl_xor(mx, sh, 64));
      const float mn = fmaxf(m_r[r], mx);
      alpha[r] = __expf(m_r[r] - mn);
      const float p0 = __expf(v0 - mn);
      const float p1 = __expf(v1 - mn);
      m_r[r] = mn;
      float ps = p0 + p1;
#pragma unroll
      for (int sh=1; sh<16; sh<<=1) ps += __shfl_xor(ps, sh, 64);
      l_r[r] = l_r[r]*alpha[r] + ps;
      // P in C-layout -> LDS (row = hi*4+r, cols lo, lo+16)
      Pw[(hi*4 + r)*LDP + lo]      = f2bf(p0);
      Pw[(hi*4 + r)*LDP + 16 + lo] = f2bf(p1);
    }
    // rescale O while LDS writes land
#pragma unroll
    for (int i=0;i<16;i++){
      accO[i][0]*=alpha[0]; accO[i][1]*=alpha[1];
      accO[i][2]*=alpha[2]; accO[i][3]*=alpha[3];
    }
    // cross-lane LDS dependency is invisible to per-thread alias analysis:
    asm volatile("s_waitcnt lgkmcnt(0)" ::: "memory");
    const bf16x8 pa = *reinterpret_cast<const bf16x8*>(&Pw[lo*LDP + 8*hi]);
    // PV: B-op frag = Vt[d = nf*16+lo][kv0 + 8*hi + j], contiguous 16B
    const unsigned short* Vp = Vbase + kv0;
#pragma unroll
    for (int nf=0;nf<16;nf++){
      bf16x8 vf = *reinterpret_cast<const bf16x8*>(Vp + (size_t)nf*16*2048);
      accO[nf] = __builtin_amdgcn_mfma_f32_16x16x32_bf16(pa, vf, accO[nf], 0,0,0);
    }
  }

  float inv[4];
#pragma unroll
  for (int r=0;r<4;r++) inv[r] = 1.0f/(l_r[r] + 1e-9f);
  float* Op = Out + ((size_t)(b*2048 + qw0 + hi*4))*256 + lo;
#pragma unroll
  for (int nf=0;nf<16;nf++)
#pragma unroll
    for (int r=0;r<4;r++)
      Op[(size_t)r*256 + nf*16] = accO[nf][r]*inv[r];
}

// ---------------------------------------------------------------------------
extern "C" void kernel_launch(void* const* d_in, const int* in_sizes, int n_in,
                              void* d_out, int out_size, void* d_ws, size_t ws_size,
                              hipStream_t stream)
{
  const float* E  = (const float*)d_in[0];
  const float* WQ = (const float*)d_in[1];
  const float* WK = (const float*)d_in[2];
  const float* WV = (const float*)d_in[3];
  const size_t elems = (size_t)8*2048*256;
  if (ws_size < 3*elems*sizeof(unsigned short)) return;  // need 25.2 MB scratch
  unsigned short* Qb = (unsigned short*)d_ws;
  unsigned short* Kb = Qb + elems;
  unsigned short* Vt = Kb + elems;

  qkv_proj_kernel<<<dim3(6,128), 256, 0, stream>>>(E, WQ, WK, WV, Qb, Kb, Vt);
  attn_kernel<<<256, 256, 0, stream>>>(Qb, Kb, Vt, (float*)d_out);
}

// Round 2
// 195.192 us; speedup vs baseline: 1.5659x; 1.5659x over previous
//
#include <hip/hip_runtime.h>
#include <stdint.h>

// ---------------------------------------------------------------------------
// SelfAttention: QKV proj (fp32 -> bf16 MFMA GEMM) + causal flash attention.
// B=8, S=2048, D=256. out fp32 [B,S,D].
// ws layout: Qb bf16 [B][S][D] (pre-scaled 1/16), Kb bf16 [B][S][D],
//            Vt bf16 [B][D][S] (transposed for PV B-operand).
//
// Round 2: attn restructured — each block owns ONE 16-row q-tile; its 4 waves
// split the causal kv-range 4-way (flash-split) and combine partials via LDS.
// 1024 blocks -> 4 blocks/CU -> 16 waves/CU (was 4), plus a balanced tile
// schedule so each CU's resident blocks sum to constant work.
// ---------------------------------------------------------------------------

typedef __attribute__((ext_vector_type(8))) short bf16x8;
typedef __attribute__((ext_vector_type(4))) float f32x4;

#define NEGF -3.0e38f
#define LDP  40   // padded LDS row stride (bf16 elems): 80B rows -> 16B-aligned b128

__device__ __forceinline__ unsigned short f2bf(float f){
  union { float f; unsigned u; } v; v.f = f;
  unsigned r = v.u + 0x7FFFu + ((v.u >> 16) & 1u);   // RNE
  return (unsigned short)(r >> 16);
}
__device__ __forceinline__ unsigned pk2(float a, float b){
  return (unsigned)f2bf(a) | ((unsigned)f2bf(b) << 16);
}

// ---------------------------------------------------------------------------
// Kernel 1: QKV projection. C[m,n] = sum_k E[m,k] * W[n,k]  (NT GEMM).
// Grid (6, 128): x = n-tile (0,1->WQ; 2,3->WK; 4,5->WV), y = m-tile (128 rows).
// ---------------------------------------------------------------------------
__global__ __launch_bounds__(256) void qkv_proj_kernel(
    const float* __restrict__ E, const float* __restrict__ WQ,
    const float* __restrict__ WK, const float* __restrict__ WV,
    unsigned short* __restrict__ Qb, unsigned short* __restrict__ Kb,
    unsigned short* __restrict__ Vt)
{
  __shared__ unsigned short As[128*LDP];
  __shared__ unsigned short Bs[128*LDP];
  const int tn = blockIdx.x;
  const int tm = blockIdx.y;
  const int m0 = tm * 128;
  const int widx = tn >> 1;                 // 0=Q 1=K 2=V
  const float* Wp = (widx==0) ? WQ : ((widx==1) ? WK : WV);
  const int nw0 = (tn & 1) * 128;           // row offset within weight

  const int t = threadIdx.x;
  const int lane = t & 63, wid = t >> 6;
  const int hi = lane >> 4, lo = lane & 15;
  const int wm = wid >> 1, wn = wid & 1;    // 2x2 wave grid, 64x64 each

  const int srow = t >> 1;                  // staging: 2 threads per row
  const int scg  = (t & 1) * 16;            // 16 floats each

  const f32x4 fzero = {0.f, 0.f, 0.f, 0.f};
  f32x4 acc[4][4];
#pragma unroll
  for (int i=0;i<4;i++)
#pragma unroll
    for (int j=0;j<4;j++) acc[i][j] = fzero;

  for (int kk = 0; kk < 256; kk += 32) {
    const float* ga = E  + (size_t)(m0  + srow)*256 + kk + scg;
    const float* gb = Wp + (size_t)(nw0 + srow)*256 + kk + scg;
    float4 va0 = *reinterpret_cast<const float4*>(ga);
    float4 va1 = *reinterpret_cast<const float4*>(ga+4);
    float4 va2 = *reinterpret_cast<const float4*>(ga+8);
    float4 va3 = *reinterpret_cast<const float4*>(ga+12);
    float4 vb0 = *reinterpret_cast<const float4*>(gb);
    float4 vb1 = *reinterpret_cast<const float4*>(gb+4);
    float4 vb2 = *reinterpret_cast<const float4*>(gb+8);
    float4 vb3 = *reinterpret_cast<const float4*>(gb+12);
    __syncthreads();   // previous iter's LDS reads done
    uint4 wv;
    wv.x = pk2(va0.x, va0.y); wv.y = pk2(va0.z, va0.w);
    wv.z = pk2(va1.x, va1.y); wv.w = pk2(va1.z, va1.w);
    *reinterpret_cast<uint4*>(&As[srow*LDP + scg]) = wv;
    wv.x = pk2(va2.x, va2.y); wv.y = pk2(va2.z, va2.w);
    wv.z = pk2(va3.x, va3.y); wv.w = pk2(va3.z, va3.w);
    *reinterpret_cast<uint4*>(&As[srow*LDP + scg + 8]) = wv;
    wv.x = pk2(vb0.x, vb0.y); wv.y = pk2(vb0.z, vb0.w);
    wv.z = pk2(vb1.x, vb1.y); wv.w = pk2(vb1.z, vb1.w);
    *reinterpret_cast<uint4*>(&Bs[srow*LDP + scg]) = wv;
    wv.x = pk2(vb2.x, vb2.y); wv.y = pk2(vb2.z, vb2.w);
    wv.z = pk2(vb3.x, vb3.y); wv.w = pk2(vb3.z, vb3.w);
    *reinterpret_cast<uint4*>(&Bs[srow*LDP + scg + 8]) = wv;
    __syncthreads();

    bf16x8 af[4], bfr[4];
#pragma unroll
    for (int f=0; f<4; f++){
      af[f]  = *reinterpret_cast<const bf16x8*>(&As[(wm*64 + f*16 + lo)*LDP + 8*hi]);
      bfr[f] = *reinterpret_cast<const bf16x8*>(&Bs[(wn*64 + f*16 + lo)*LDP + 8*hi]);
    }
#pragma unroll
    for (int i=0;i<4;i++)
#pragma unroll
      for (int j=0;j<4;j++)
        acc[i][j] = __builtin_amdgcn_mfma_f32_16x16x32_bf16(af[i], bfr[j], acc[i][j], 0,0,0);
  }

  // Epilogue. C/D layout: row = (lane>>4)*4 + reg, col = lane&15.
  const int b  = m0 >> 11;
  const int s0 = m0 & 2047;
  if (widx < 2) {
    unsigned short* Out = (widx==0) ? Qb : Kb;
    const float mul = (widx==0) ? 0.0625f : 1.0f;   // fold 1/sqrt(D) into Q (exact pow2)
#pragma unroll
    for (int i=0;i<4;i++){
      const int mrow = m0 + wm*64 + i*16 + hi*4;
#pragma unroll
      for (int j=0;j<4;j++){
        const int col = nw0 + wn*64 + j*16 + lo;
#pragma unroll
        for (int r=0;r<4;r++)
          Out[(size_t)(mrow + r)*256 + col] = f2bf(acc[i][j][r]*mul);
      }
    }
  } else {
    // V stored transposed: Vt[b][d][s]
#pragma unroll
    for (int i=0;i<4;i++){
      const int sr = s0 + wm*64 + i*16 + hi*4;
#pragma unroll
      for (int j=0;j<4;j++){
        const int d = nw0 + wn*64 + j*16 + lo;
        unsigned short* vp = Vt + ((size_t)b*256 + d)*2048 + sr;
#pragma unroll
        for (int r=0;r<4;r++) vp[r] = f2bf(acc[i][j][r]);
      }
    }
  }
}

// ---------------------------------------------------------------------------
// Kernel 2: causal flash attention, kv-split-4 within each block.
// Grid 1024: bid -> (round, cu-slot, batch). batch = bid&7 keeps batch->XCD
// L2 pinning. Each block = one 16-row q-tile; wave w handles kv-chunk w of
// the causal range; partials combined via LDS (exact f32 flash-combine).
// Balanced schedule: CU-resident tiles {c, 63-c, 64+c, 127-c} sum to 254.
// ---------------------------------------------------------------------------
__global__ __launch_bounds__(256, 4) void attn_kernel(
    const unsigned short* __restrict__ Qb, const unsigned short* __restrict__ Kb,
    const unsigned short* __restrict__ Vt, float* __restrict__ Out)
{
  __shared__ unsigned short Pl[4][16*LDP];  // per-wave P transpose buffer
  __shared__ float Ml[4][16], Ll[4][16];    // per-wave running max / denom
  __shared__ float Os[4][16][65];           // phased O-combine (65: bank stagger)

  const int bid = blockIdx.x;
  const int pb  = bid & 255;
  const int rnd = bid >> 8;                 // 0..3
  const int b   = pb & 7;                   // batch == XCD
  const int c   = pb >> 3;                  // 0..31 (CU slot within XCD)
  int tq;
  if      (rnd == 0) tq = c;
  else if (rnd == 1) tq = 63 - c;
  else if (rnd == 2) tq = 64 + c;
  else               tq = 127 - c;
  const int qb = tq * 16;                   // this block's q-tile base row

  const int t = threadIdx.x;
  const int lane = t & 63, w = t >> 6;
  const int hi = lane >> 4, lo = lane & 15;

  // kv-split: wave w takes units [w*ck, (w+1)*ck) of the causal range
  const int nkv = (qb + 47) >> 5;           // 32-kv units covering rows 0..qb+15
  const int ck  = (nkv + 3) >> 2;
  const int u0  = w * ck;
  const int u1  = min((w + 1) * ck, nkv);

  // Q fragments in registers (A-op: row=lo, k=8*hi+j) — same rows for all waves
  const unsigned short* Qp = Qb + ((size_t)(b*2048 + qb + lo))*256 + 8*hi;
  bf16x8 qf[8];
#pragma unroll
  for (int kc=0;kc<8;kc++) qf[kc] = *reinterpret_cast<const bf16x8*>(Qp + kc*32);

  const f32x4 fzero = {0.f, 0.f, 0.f, 0.f};
  f32x4 accO[16];
#pragma unroll
  for (int i=0;i<16;i++) accO[i] = fzero;
  float m_r[4] = {NEGF,NEGF,NEGF,NEGF};
  float l_r[4] = {0.f,0.f,0.f,0.f};

  const unsigned short* Kbase = Kb + (size_t)b*2048*256;
  const unsigned short* Vbase = Vt + (size_t)b*256*2048 + (size_t)lo*2048 + 8*hi;
  unsigned short* Pw = Pl[w];

  for (int it = u0; it < u1; ++it){
    const int kv0 = it*32;
    // S-tile = Q * K^T (scale pre-folded into Q)
    f32x4 s0v = fzero, s1v = fzero;
    const unsigned short* Kp = Kbase + (size_t)(kv0 + lo)*256 + 8*hi;
#pragma unroll
    for (int kc=0;kc<8;kc++){
      bf16x8 k0 = *reinterpret_cast<const bf16x8*>(Kp + kc*32);
      bf16x8 k1 = *reinterpret_cast<const bf16x8*>(Kp + 16*256 + kc*32);
      s0v = __builtin_amdgcn_mfma_f32_16x16x32_bf16(qf[kc], k0, s0v, 0,0,0);
      s1v = __builtin_amdgcn_mfma_f32_16x16x32_bf16(qf[kc], k1, s1v, 0,0,0);
    }
    const bool need_mask = (kv0 + 31) > qb;
    float alpha[4];
#pragma unroll
    for (int r=0;r<4;r++){
      float v0 = s0v[r], v1 = s1v[r];
      if (need_mask){
        const int q = qb + hi*4 + r;
        if (kv0 + lo      > q) v0 = NEGF;
        if (kv0 + 16 + lo > q) v1 = NEGF;
      }
      float mx = fmaxf(v0, v1);
#pragma unroll
      for (int sh=1; sh<16; sh<<=1) mx = fmaxf(mx, __shfl_xor(mx, sh, 64));
      const float mn = fmaxf(m_r[r], mx);
      alpha[r] = __expf(m_r[r] - mn);
      const float p0 = __expf(v0 - mn);
      const float p1 = __expf(v1 - mn);
      m_r[r] = mn;
      float ps = p0 + p1;
#pragma unroll
      for (int sh=1; sh<16; sh<<=1) ps += __shfl_xor(ps, sh, 64);
      l_r[r] = l_r[r]*alpha[r] + ps;
      // P in C-layout -> LDS (row = hi*4+r, cols lo, lo+16)
      Pw[(hi*4 + r)*LDP + lo]      = f2bf(p0);
      Pw[(hi*4 + r)*LDP + 16 + lo] = f2bf(p1);
    }
    // rescale O while LDS writes land
#pragma unroll
    for (int i=0;i<16;i++){
      accO[i][0]*=alpha[0]; accO[i][1]*=alpha[1];
      accO[i][2]*=alpha[2]; accO[i][3]*=alpha[3];
    }
    // cross-lane LDS dependency is invisible to per-thread alias analysis:
    asm volatile("s_waitcnt lgkmcnt(0)" ::: "memory");
    const bf16x8 pa = *reinterpret_cast<const bf16x8*>(&Pw[lo*LDP + 8*hi]);
    // PV: B-op frag = Vt[d = nf*16+lo][kv0 + 8*hi + j], contiguous 16B
    const unsigned short* Vp = Vbase + kv0;
#pragma unroll
    for (int nf=0;nf<16;nf++){
      bf16x8 vf = *reinterpret_cast<const bf16x8*>(Vp + (size_t)nf*16*2048);
      accO[nf] = __builtin_amdgcn_mfma_f32_16x16x32_bf16(pa, vf, accO[nf], 0,0,0);
    }
  }

  // ---- publish per-wave m, l ----
  if (lo == 0){
#pragma unroll
    for (int r=0;r<4;r++){ Ml[w][hi*4+r] = m_r[r]; Ll[w][hi*4+r] = l_r[r]; }
  }
  __syncthreads();

  // ---- per-thread combine scales for its 4 output rows ----
  const int colc = t & 63;
  const int rg   = t >> 6;                  // row group 0..3 (rows rg*4+rr)
  float sc[4][4], invl[4];
#pragma unroll
  for (int rr=0; rr<4; ++rr){
    const int row = rg*4 + rr;
    float M = fmaxf(fmaxf(Ml[0][row], Ml[1][row]), fmaxf(Ml[2][row], Ml[3][row]));
    float L = 0.f;
#pragma unroll
    for (int wv=0; wv<4; ++wv){
      float s = __expf(Ml[wv][row] - M);
      sc[rr][wv] = s;
      L += s * Ll[wv][row];
    }
    invl[rr] = 1.0f/(L + 1e-9f);
  }

  // ---- phased O-combine through 16KB LDS: cols [p4*64, p4*64+64) ----
  float* Ob = Out + ((size_t)(b*2048 + qb))*256;
#pragma unroll
  for (int p4=0; p4<4; ++p4){
    __syncthreads();
#pragma unroll
    for (int q=0;q<4;q++){
      const int nf = p4*4 + q;
#pragma unroll
      for (int r=0;r<4;r++) Os[w][hi*4+r][q*16+lo] = accO[nf][r];
    }
    __syncthreads();
#pragma unroll
    for (int rr=0;rr<4;rr++){
      const int row = rg*4 + rr;
      float acc = sc[rr][0]*Os[0][row][colc] + sc[rr][1]*Os[1][row][colc]
                + sc[rr][2]*Os[2][row][colc] + sc[rr][3]*Os[3][row][colc];
      Ob[(size_t)row*256 + p4*64 + colc] = acc * invl[rr];
    }
  }
}

// ---------------------------------------------------------------------------
extern "C" void kernel_launch(void* const* d_in, const int* in_sizes, int n_in,
                              void* d_out, int out_size, void* d_ws, size_t ws_size,
                              hipStream_t stream)
{
  const float* E  = (const float*)d_in[0];
  const float* WQ = (const float*)d_in[1];
  const float* WK = (const float*)d_in[2];
  const float* WV = (const float*)d_in[3];
  const size_t elems = (size_t)8*2048*256;
  if (ws_size < 3*elems*sizeof(unsigned short)) return;  // need 25.2 MB scratch
  unsigned short* Qb = (unsigned short*)d_ws;
  unsigned short* Kb = Qb + elems;
  unsigned short* Vt = Kb + elems;

  qkv_proj_kernel<<<dim3(6,128), 256, 0, stream>>>(E, WQ, WK, WV, Qb, Kb, Vt);
  attn_kernel<<<1024, 256, 0, stream>>>(Qb, Kb, Vt, (float*)d_out);
}

// Round 3
// 120.927 us; speedup vs baseline: 2.5275x; 1.6141x over previous
//
#include <hip/hip_runtime.h>
#include <stdint.h>

// ---------------------------------------------------------------------------
// SelfAttention: QKV proj (fp32 -> bf16 MFMA GEMM) + causal flash attention.
// B=8, S=2048, D=256. out fp32 [B,S,D].
// ws: Qb bf16 [B][S][D] linear (pre-scaled 1/16),
//     Kb bf16 [B][S][D] with per-row 16B-granule XOR swizzle (g ^= s&7),
//     Vt bf16 [B][D][S] linear (transposed for PV B-operand).
//
// Round 3: attn restructured for throughput:
//  - 32-row q-tiles, grid 512 (2 blocks/CU), 4 waves with 2-D split:
//    QK by (qfrag x kvfrag) quadrant, PV by d-columns (V/K read ~once/block).
//  - K/V double-buffer staged in LDS via global_load_lds, 1 unit ahead.
//  - softmax via LDS S-matrix: 8 rows/wave, 3-step shfl over 8 lanes.
//  - pairing schedule g(s) so co-resident blocks sum to constant work.
// ---------------------------------------------------------------------------

typedef __attribute__((ext_vector_type(8))) short bf16x8;
typedef __attribute__((ext_vector_type(4))) float f32x4;

#define NEGF -3.0e38f
#define LDP  40   // proj LDS pad; also P-tile row stride (80B, 16B-aligned)

__device__ __forceinline__ unsigned short f2bf(float f){
  union { float f; unsigned u; } v; v.f = f;
  unsigned r = v.u + 0x7FFFu + ((v.u >> 16) & 1u);   // RNE
  return (unsigned short)(r >> 16);
}
__device__ __forceinline__ unsigned pk2(float a, float b){
  return (unsigned)f2bf(a) | ((unsigned)f2bf(b) << 16);
}

// ---------------------------------------------------------------------------
// Kernel 1: QKV projection. C[m,n] = sum_k E[m,k] * W[n,k]  (NT GEMM).
// Grid (6, 128). K output gets the granule swizzle; Q,V linear.
// ---------------------------------------------------------------------------
__global__ __launch_bounds__(256) void qkv_proj_kernel(
    const float* __restrict__ E, const float* __restrict__ WQ,
    const float* __restrict__ WK, const float* __restrict__ WV,
    unsigned short* __restrict__ Qb, unsigned short* __restrict__ Kb,
    unsigned short* __restrict__ Vt)
{
  __shared__ unsigned short As[128*LDP];
  __shared__ unsigned short Bs[128*LDP];
  const int tn = blockIdx.x;
  const int tm = blockIdx.y;
  const int m0 = tm * 128;
  const int widx = tn >> 1;                 // 0=Q 1=K 2=V
  const float* Wp = (widx==0) ? WQ : ((widx==1) ? WK : WV);
  const int nw0 = (tn & 1) * 128;

  const int t = threadIdx.x;
  const int lane = t & 63, wid = t >> 6;
  const int hi = lane >> 4, lo = lane & 15;
  const int wm = wid >> 1, wn = wid & 1;

  const int srow = t >> 1;
  const int scg  = (t & 1) * 16;

  const f32x4 fzero = {0.f, 0.f, 0.f, 0.f};
  f32x4 acc[4][4];
#pragma unroll
  for (int i=0;i<4;i++)
#pragma unroll
    for (int j=0;j<4;j++) acc[i][j] = fzero;

  for (int kk = 0; kk < 256; kk += 32) {
    const float* ga = E  + (size_t)(m0  + srow)*256 + kk + scg;
    const float* gb = Wp + (size_t)(nw0 + srow)*256 + kk + scg;
    float4 va0 = *reinterpret_cast<const float4*>(ga);
    float4 va1 = *reinterpret_cast<const float4*>(ga+4);
    float4 va2 = *reinterpret_cast<const float4*>(ga+8);
    float4 va3 = *reinterpret_cast<const float4*>(ga+12);
    float4 vb0 = *reinterpret_cast<const float4*>(gb);
    float4 vb1 = *reinterpret_cast<const float4*>(gb+4);
    float4 vb2 = *reinterpret_cast<const float4*>(gb+8);
    float4 vb3 = *reinterpret_cast<const float4*>(gb+12);
    __syncthreads();
    uint4 wv;
    wv.x = pk2(va0.x, va0.y); wv.y = pk2(va0.z, va0.w);
    wv.z = pk2(va1.x, va1.y); wv.w = pk2(va1.z, va1.w);
    *reinterpret_cast<uint4*>(&As[srow*LDP + scg]) = wv;
    wv.x = pk2(va2.x, va2.y); wv.y = pk2(va2.z, va2.w);
    wv.z = pk2(va3.x, va3.y); wv.w = pk2(va3.z, va3.w);
    *reinterpret_cast<uint4*>(&As[srow*LDP + scg + 8]) = wv;
    wv.x = pk2(vb0.x, vb0.y); wv.y = pk2(vb0.z, vb0.w);
    wv.z = pk2(vb1.x, vb1.y); wv.w = pk2(vb1.z, vb1.w);
    *reinterpret_cast<uint4*>(&Bs[srow*LDP + scg]) = wv;
    wv.x = pk2(vb2.x, vb2.y); wv.y = pk2(vb2.z, vb2.w);
    wv.z = pk2(vb3.x, vb3.y); wv.w = pk2(vb3.z, vb3.w);
    *reinterpret_cast<uint4*>(&Bs[srow*LDP + scg + 8]) = wv;
    __syncthreads();

    bf16x8 af[4], bfr[4];
#pragma unroll
    for (int f=0; f<4; f++){
      af[f]  = *reinterpret_cast<const bf16x8*>(&As[(wm*64 + f*16 + lo)*LDP + 8*hi]);
      bfr[f] = *reinterpret_cast<const bf16x8*>(&Bs[(wn*64 + f*16 + lo)*LDP + 8*hi]);
    }
#pragma unroll
    for (int i=0;i<4;i++)
#pragma unroll
      for (int j=0;j<4;j++)
        acc[i][j] = __builtin_amdgcn_mfma_f32_16x16x32_bf16(af[i], bfr[j], acc[i][j], 0,0,0);
  }

  // Epilogue. C/D layout: row = (lane>>4)*4 + reg, col = lane&15.
  const int b  = m0 >> 11;
  const int s0 = m0 & 2047;
  if (widx == 0) {
#pragma unroll
    for (int i=0;i<4;i++){
      const int mrow = m0 + wm*64 + i*16 + hi*4;
#pragma unroll
      for (int j=0;j<4;j++){
        const int col = nw0 + wn*64 + j*16 + lo;
#pragma unroll
        for (int r=0;r<4;r++)
          Qb[(size_t)(mrow + r)*256 + col] = f2bf(acc[i][j][r]*0.0625f);
      }
    }
  } else if (widx == 1) {
    // K with granule swizzle: col' = ((col>>3)^(s&7))*8 + (col&7)
#pragma unroll
    for (int i=0;i<4;i++){
      const int mrow = m0 + wm*64 + i*16 + hi*4;
#pragma unroll
      for (int j=0;j<4;j++){
        const int col = nw0 + wn*64 + j*16 + lo;
#pragma unroll
        for (int r=0;r<4;r++){
          const int s = mrow + r;
          const int scol = (((col>>3) ^ (s&7))<<3) | (col&7);
          Kb[(size_t)s*256 + scol] = f2bf(acc[i][j][r]);
        }
      }
    }
  } else {
    // V stored transposed: Vt[b][d][s], linear
#pragma unroll
    for (int i=0;i<4;i++){
      const int sr = s0 + wm*64 + i*16 + hi*4;
#pragma unroll
      for (int j=0;j<4;j++){
        const int d = nw0 + wn*64 + j*16 + lo;
        unsigned short* vp = Vt + ((size_t)b*256 + d)*2048 + sr;
#pragma unroll
        for (int r=0;r<4;r++) vp[r] = f2bf(acc[i][j][r]);
      }
    }
  }
}

// ---------------------------------------------------------------------------
// Kernel 2: causal flash attention. 512 blocks x 256 threads.
// Block = 32 q-rows. Waves: QK quadrant (qf=w>>1, ks=w&1); PV d-slice w*64.
// KV units of 32 staged (K 16KB + V 16KB) double-buffered via global_load_lds.
// ---------------------------------------------------------------------------
__global__ __launch_bounds__(256, 2) void attn_kernel(
    const unsigned short* __restrict__ Qb, const unsigned short* __restrict__ Kb,
    const unsigned short* __restrict__ Vt, float* __restrict__ Out)
{
  __shared__ unsigned short Kt[2][32*256];    // K tile, swizzled granules
  __shared__ unsigned short Vts[2][256*32];   // V tile [d][kv], 64B rows
  __shared__ float  Sl[32*36];                // S matrix, 144B rows
  __shared__ unsigned short Pl2[32*LDP];      // P bf16, 80B rows
  __shared__ float  Al[32];                   // per-row alpha (this unit)
  __shared__ float  Ll[32];                   // final denominators

  const int bid  = blockIdx.x;
  const int b    = bid & 7;
  const int slot = bid >> 3;                            // 0..63
  const int tile = (slot < 32) ? (63 - slot) : (slot - 32); // pair-sum 63
  const int qb   = tile * 32;

  const int t = threadIdx.x;
  const int lane = t & 63, w = t >> 6;
  const int hi = lane >> 4, lo = lane & 15;
  const int qf = w >> 1, ks = w & 1;          // QK quadrant
  const int rr = lane >> 3, c8 = lane & 7;    // softmax: row rr, col chunk c8
  const int srow = w*8 + rr;                  // softmax row owned (local 0..31)

  const char* Kbb = (const char*)Kb + (size_t)b*2048*512;
  const char* Vtb = (const char*)Vt + (size_t)b*256*4096;

  // Q A-fragment for this wave's qfrag: row = qb + qf*16 + lo, k = kc*32+8hi+j
  const unsigned short* Qp = Qb + ((size_t)(b*2048 + qb + qf*16 + lo))*256 + 8*hi;
  bf16x8 qfr[8];
#pragma unroll
  for (int kc=0;kc<8;kc++) qfr[kc] = *reinterpret_cast<const bf16x8*>(Qp + kc*32);

  const f32x4 fzero = {0.f,0.f,0.f,0.f};
  f32x4 accO[2][4];
#pragma unroll
  for (int i=0;i<2;i++)
#pragma unroll
    for (int j=0;j<4;j++) accO[i][j] = fzero;
  float m_run = NEGF, l_run = 0.f;

  const int nu = tile + 1;                    // 32-kv units in causal range

  // ---- staging helpers (linear copies; K swizzle pre-baked in global) ----
  auto stage = [&](int u, int buf){
    const char* gk = Kbb + (size_t)u*32*512;  // contiguous 16KB
    char* lk = (char*)Kt[buf];
#pragma unroll
    for (int c=0;c<4;c++){
      const int off = c*4096 + t*16;
      __builtin_amdgcn_global_load_lds(
        (const __attribute__((address_space(1))) unsigned int*)(gk + off),
        (__attribute__((address_space(3))) unsigned int*)(lk + off), 16, 0, 0);
    }
    char* lv = (char*)Vts[buf];
    const size_t kvb = (size_t)u*64;          // kv0*2 bytes
#pragma unroll
    for (int c=0;c<4;c++){
      const int off = c*4096 + t*16;
      const int d = off >> 6, soff = off & 63;
      __builtin_amdgcn_global_load_lds(
        (const __attribute__((address_space(1))) unsigned int*)(Vtb + (size_t)d*4096 + kvb + soff),
        (__attribute__((address_space(3))) unsigned int*)(lv + off), 16, 0, 0);
    }
  };

  stage(0, 0);
  asm volatile("s_waitcnt vmcnt(0)" ::: "memory");
  __syncthreads();

  for (int u = 0; u < nu; ++u){
    const int bb = u & 1;
    // ---- QK quadrant: S[qf*16.., ks*16..] ----
    f32x4 sv = fzero;
    const char* kt = (const char*)Kt[bb];
#pragma unroll
    for (int kc=0;kc<8;kc++){
      const int r = ks*16 + lo;
      bf16x8 kf = *reinterpret_cast<const bf16x8*>(
          kt + r*512 + (((kc*4 + hi) ^ (r&7))<<4));
      sv = __builtin_amdgcn_mfma_f32_16x16x32_bf16(qfr[kc], kf, sv, 0,0,0);
    }
#pragma unroll
    for (int r=0;r<4;r++)
      Sl[(qf*16 + hi*4 + r)*36 + ks*16 + lo] = sv[r];
    __syncthreads();                                    // B1: S ready

    if (u + 1 < nu) stage(u+1, bb^1);                   // prefetch next unit

    // ---- softmax: this lane reduces row `srow`, cols c8*4..c8*4+3 ----
    f32x4 s4 = *reinterpret_cast<const f32x4*>(&Sl[srow*36 + c8*4]);
    if (u == tile){
#pragma unroll
      for (int j=0;j<4;j++) if (c8*4 + j > srow) s4[j] = NEGF;
    }
    float mx = fmaxf(fmaxf(s4[0], s4[1]), fmaxf(s4[2], s4[3]));
#pragma unroll
    for (int sh=1; sh<8; sh<<=1) mx = fmaxf(mx, __shfl_xor(mx, sh, 64));
    const float mn = fmaxf(m_run, mx);
    const float alpha = __expf(m_run - mn);
    float p0 = __expf(s4[0]-mn), p1 = __expf(s4[1]-mn);
    float p2 = __expf(s4[2]-mn), p3 = __expf(s4[3]-mn);
    m_run = mn;
    float ps = (p0+p1) + (p2+p3);
#pragma unroll
    for (int sh=1; sh<8; sh<<=1) ps += __shfl_xor(ps, sh, 64);
    l_run = l_run*alpha + ps;
    if (c8 == 0) Al[srow] = alpha;
    uint2 pw; pw.x = pk2(p0,p1); pw.y = pk2(p2,p3);
    *reinterpret_cast<uint2*>((char*)Pl2 + srow*80 + c8*8) = pw;
    __syncthreads();                                    // B2: P, Al ready

    // ---- PV d-slice: O[:, w*64 .. w*64+63] ----
    float al[2][4];
#pragma unroll
    for (int q2=0;q2<2;q2++)
#pragma unroll
      for (int r=0;r<4;r++) al[q2][r] = Al[q2*16 + hi*4 + r];
#pragma unroll
    for (int q2=0;q2<2;q2++)
#pragma unroll
      for (int nf=0;nf<4;nf++)
#pragma unroll
        for (int r=0;r<4;r++) accO[q2][nf][r] *= al[q2][r];

    bf16x8 paf[2];
#pragma unroll
    for (int q2=0;q2<2;q2++)
      paf[q2] = *reinterpret_cast<const bf16x8*>((char*)Pl2 + (q2*16+lo)*80 + hi*16);
    const char* vt = (const char*)Vts[bb];
#pragma unroll
    for (int nf=0;nf<4;nf++){
      const int d = w*64 + nf*16 + lo;
      bf16x8 vf = *reinterpret_cast<const bf16x8*>(vt + d*64 + hi*16);
#pragma unroll
      for (int q2=0;q2<2;q2++)
        accO[q2][nf] = __builtin_amdgcn_mfma_f32_16x16x32_bf16(paf[q2], vf, accO[q2][nf], 0,0,0);
    }
    asm volatile("s_waitcnt vmcnt(0)" ::: "memory");    // staging landed
    __syncthreads();                                    // B3: buffers reusable
  }

  if (c8 == 0) Ll[srow] = l_run;
  __syncthreads();

  float* Ob = Out + ((size_t)(b*2048 + qb))*256 + w*64;
#pragma unroll
  for (int q2=0;q2<2;q2++){
#pragma unroll
    for (int r=0;r<4;r++){
      const int q = q2*16 + hi*4 + r;
      const float inv = 1.0f/(Ll[q] + 1e-9f);
#pragma unroll
      for (int nf=0;nf<4;nf++)
        Ob[(size_t)q*256 + nf*16 + lo] = accO[q2][nf][r]*inv;
    }
  }
}

// ---------------------------------------------------------------------------
extern "C" void kernel_launch(void* const* d_in, const int* in_sizes, int n_in,
                              void* d_out, int out_size, void* d_ws, size_t ws_size,
                              hipStream_t stream)
{
  const float* E  = (const float*)d_in[0];
  const float* WQ = (const float*)d_in[1];
  const float* WK = (const float*)d_in[2];
  const float* WV = (const float*)d_in[3];
  const size_t elems = (size_t)8*2048*256;
  if (ws_size < 3*elems*sizeof(unsigned short)) return;
  unsigned short* Qb = (unsigned short*)d_ws;
  unsigned short* Kb = Qb + elems;
  unsigned short* Vt = Kb + elems;

  qkv_proj_kernel<<<dim3(6,128), 256, 0, stream>>>(E, WQ, WK, WV, Qb, Kb, Vt);
  attn_kernel<<<512, 256, 0, stream>>>(Qb, Kb, Vt, (float*)d_out);
}

// Round 4
// 109.574 us; speedup vs baseline: 2.7894x; 1.1036x over previous
//
#include <hip/hip_runtime.h>
#include <stdint.h>

// ---------------------------------------------------------------------------
// SelfAttention: QKV proj (fp32 -> bf16 MFMA GEMM) + causal flash attention.
// B=8, S=2048, D=256. out fp32 [B,S,D].
// ws: Qb bf16 [B][S][D] linear (pre-scaled 1/16),
//     Kb bf16 [B][S][D] with per-row 16B-granule XOR swizzle (g ^= s&7),
//     Vt bf16 [B][D][S] linear (transposed for PV B-operand),
//     Wb bf16 [3][8kk][256n][4g] pre-swizzled weights (B-tile staging format),
//     P1 f32 [8][32][32][256] chunk-1 partials, ML f32 [512][32][2] (m,l).
//
// Round 4:
//  - proj rewritten: E read ONCE (block = 32 rows x full N, loops Q/K/V),
//    weights pre-converted+pre-swizzled so B staging is pure global_load_lds.
//  - attn: split-K across blocks for tiles>=32 (768 blocks -> steady 8
//    waves/CU with dynamic balance), exact flash combine kernel.
//  - softmax S-matrix LDS read 8-way bank conflict fixed via XOR swizzle.
// ---------------------------------------------------------------------------

typedef __attribute__((ext_vector_type(8))) short bf16x8;
typedef __attribute__((ext_vector_type(4))) float f32x4;

#define NEGF -3.0e38f

__device__ __forceinline__ unsigned short f2bf(float f){
  union { float f; unsigned u; } v; v.f = f;
  unsigned r = v.u + 0x7FFFu + ((v.u >> 16) & 1u);   // RNE
  return (unsigned short)(r >> 16);
}
__device__ __forceinline__ unsigned pk2(float a, float b){
  return (unsigned)f2bf(a) | ((unsigned)f2bf(b) << 16);
}

// ---------------------------------------------------------------------------
// Kernel 0: weight convert. Wb[widx][kk][n][g'] holds W[n][kk*32+(g'^(n&3))*8+j]
// so that a LINEAR global_load_lds copy yields a bank-conflict-free B-tile.
// ---------------------------------------------------------------------------
__global__ void wconv_kernel(const float* __restrict__ WQ, const float* __restrict__ WK,
                             const float* __restrict__ WV, unsigned short* __restrict__ Wb)
{
  const int widx = blockIdx.x, kk = blockIdx.y, n = threadIdx.x;
  const float* W = (widx==0) ? WQ : ((widx==1) ? WK : WV);
  unsigned short* dst = Wb + (size_t)widx*65536 + kk*8192 + n*32;
#pragma unroll
  for (int gp=0; gp<4; ++gp){
    const int g = gp ^ (n & 3);
    const float* src = W + (size_t)n*256 + kk*32 + g*8;
    float4 a = *reinterpret_cast<const float4*>(src);
    float4 c = *reinterpret_cast<const float4*>(src + 4);
    uint4 v; v.x = pk2(a.x,a.y); v.y = pk2(a.z,a.w); v.z = pk2(c.x,c.y); v.w = pk2(c.z,c.w);
    *reinterpret_cast<uint4*>(dst + gp*8) = v;
  }
}

// ---------------------------------------------------------------------------
// Kernel 1: QKV projection. Block = 32 m-rows x 256 n-cols, loops widx 0..2.
// A (E tile) staged ONCE with f32->bf16 cvt + XOR-swizzled granules;
// B staged per k-iter via global_load_lds (double-buffered, zero VALU).
// ---------------------------------------------------------------------------
__global__ __launch_bounds__(256) void qkv_proj_kernel(
    const float* __restrict__ E, const unsigned short* __restrict__ Wb,
    unsigned short* __restrict__ Qb, unsigned short* __restrict__ Kb,
    unsigned short* __restrict__ Vt)
{
  __shared__ unsigned short As[32*256];     // 16KB, granule g' = g ^ (row&7)
  __shared__ unsigned short Bs[2][8192];    // 2 x 16KB, pre-swizzled in Wb

  const int m0 = blockIdx.x * 32;
  const int b  = m0 >> 11;
  const int sb = m0 & 2047;
  const int t = threadIdx.x, lane = t & 63, w = t >> 6;
  const int hi = lane >> 4, lo = lane & 15;

  auto stageB = [&](int widx, int kk, int buf){
    const char* src = (const char*)Wb + widx*131072 + kk*16384;
    char* dst = (char*)Bs[buf];
#pragma unroll
    for (int c=0;c<4;c++){
      const int off = c*4096 + t*16;
      __builtin_amdgcn_global_load_lds(
        (const __attribute__((address_space(1))) unsigned int*)(src + off),
        (__attribute__((address_space(3))) unsigned int*)(dst + off), 16, 0, 0);
    }
  };

  stageB(0, 0, 0);
  // ---- stage A once: thread t -> row t>>3, cols (t&7)*32..+31 ----
  {
    const int r = t >> 3, c0 = (t & 7) * 32;
    const float* ga = E + (size_t)(m0 + r)*256 + c0;
#pragma unroll
    for (int gg=0; gg<4; ++gg){
      float4 x = *reinterpret_cast<const float4*>(ga + gg*8);
      float4 y = *reinterpret_cast<const float4*>(ga + gg*8 + 4);
      uint4 v; v.x = pk2(x.x,x.y); v.y = pk2(x.z,x.w); v.z = pk2(y.x,y.y); v.w = pk2(y.z,y.w);
      const int g = (t & 7)*4 + gg;
      *reinterpret_cast<uint4*>((char*)As + r*512 + ((g ^ (r & 7)) << 4)) = v;
    }
  }
  __syncthreads();

  const f32x4 fzero = {0.f,0.f,0.f,0.f};
  for (int widx=0; widx<3; ++widx){
    f32x4 acc[2][4];
#pragma unroll
    for (int mi=0;mi<2;mi++)
#pragma unroll
      for (int f=0;f<4;f++) acc[mi][f] = fzero;
    if (widx) stageB(widx, 0, 0);

    for (int kk=0; kk<8; ++kk){
      const int bb = kk & 1;
      asm volatile("s_waitcnt vmcnt(0)" ::: "memory");
      __syncthreads();
      if (kk < 7) stageB(widx, kk+1, bb^1);

      bf16x8 afr[2], bfr[4];
#pragma unroll
      for (int mi=0;mi<2;mi++){
        const int r = mi*16 + lo;
        afr[mi] = *reinterpret_cast<const bf16x8*>(
            (const char*)As + r*512 + (((kk*4 + hi) ^ (r & 7)) << 4));
      }
#pragma unroll
      for (int f=0;f<4;f++){
        const int n = w*64 + f*16 + lo;
        bfr[f] = *reinterpret_cast<const bf16x8*>(
            (const char*)Bs[bb] + n*64 + ((hi ^ (n & 3)) << 4));
      }
#pragma unroll
      for (int mi=0;mi<2;mi++)
#pragma unroll
        for (int f=0;f<4;f++)
          acc[mi][f] = __builtin_amdgcn_mfma_f32_16x16x32_bf16(afr[mi], bfr[f], acc[mi][f], 0,0,0);
    }

    // ---- epilogue (C/D layout: row = hi*4+r within 16-tile, col = lo) ----
    if (widx == 0){
#pragma unroll
      for (int mi=0;mi<2;mi++)
#pragma unroll
        for (int f=0;f<4;f++){
          const int col = w*64 + f*16 + lo;
#pragma unroll
          for (int r=0;r<4;r++)
            Qb[(size_t)(m0 + mi*16 + hi*4 + r)*256 + col] = f2bf(acc[mi][f][r]*0.0625f);
        }
    } else if (widx == 1){
#pragma unroll
      for (int mi=0;mi<2;mi++)
#pragma unroll
        for (int f=0;f<4;f++){
          const int col = w*64 + f*16 + lo;
#pragma unroll
          for (int r=0;r<4;r++){
            const int s = m0 + mi*16 + hi*4 + r;
            const int scol = (((col>>3) ^ (s&7))<<3) | (col&7);
            Kb[(size_t)s*256 + scol] = f2bf(acc[mi][f][r]);
          }
        }
    } else {
#pragma unroll
      for (int mi=0;mi<2;mi++)
#pragma unroll
        for (int f=0;f<4;f++){
          const int d = w*64 + f*16 + lo;
          unsigned short* vp = Vt + ((size_t)b*256 + d)*2048 + sb + mi*16 + hi*4;
#pragma unroll
          for (int r=0;r<4;r++) vp[r] = f2bf(acc[mi][f][r]);
        }
    }
  }
}

// ---------------------------------------------------------------------------
// Kernel 2: causal flash attention, split-K blocks + XOR-swizzled softmax LDS.
// split: sidx<64 -> tiles 63..32, 2 kv-chunks each (mode 1/2 = partial);
//        sidx>=64 -> tiles 31..0 whole (mode 0 = final write).
// ---------------------------------------------------------------------------
__global__ __launch_bounds__(256, 2) void attn_kernel(
    const unsigned short* __restrict__ Qb, const unsigned short* __restrict__ Kb,
    const unsigned short* __restrict__ Vt, float* __restrict__ Out,
    const int split, float* __restrict__ P1, float* __restrict__ ML)
{
  __shared__ unsigned short Kt[2][32*256];    // K tile, swizzled granules
  __shared__ unsigned short Vts[2][256*32];   // V tile [d][kv], 64B rows
  __shared__ float  Sl[32*36];                // S matrix, chunk ^= row&7 swizzle
  __shared__ unsigned short Pl2[32*40];       // P bf16, 80B rows
  __shared__ float Al[32];                    // per-row alpha (this unit)
  __shared__ float Ll[32];                    // final denominators

  const int bid  = blockIdx.x;
  const int sidx = bid >> 3;
  const int b    = bid & 7;                   // batch == XCD
  int tile, u0, u1, mode, pidx;
  if (split){
    if (sidx < 64){
      tile = 63 - (sidx >> 1);
      const int chunk = sidx & 1;
      const int half = (tile + 2) >> 1;       // ceil((tile+1)/2)
      u0 = chunk ? half : 0;
      u1 = chunk ? (tile + 1) : half;
      mode = 1 + chunk;
      pidx = (b*32 + (tile - 32))*2 + chunk;
    } else { tile = 95 - sidx; u0 = 0; u1 = tile + 1; mode = 0; pidx = 0; }
  } else {
    tile = (sidx < 32) ? (63 - sidx) : (sidx - 32);
    u0 = 0; u1 = tile + 1; mode = 0; pidx = 0;
  }
  const int qb = tile * 32;

  const int t = threadIdx.x;
  const int lane = t & 63, w = t >> 6;
  const int hi = lane >> 4, lo = lane & 15;
  const int qf = w >> 1, ks = w & 1;          // QK quadrant
  const int rr = lane >> 3, c8 = lane & 7;    // softmax: row rr, col chunk c8
  const int srow = w*8 + rr;                  // softmax row owned (local 0..31)

  const char* Kbb = (const char*)Kb + (size_t)b*2048*512;
  const char* Vtb = (const char*)Vt + (size_t)b*256*4096;

  const unsigned short* Qp = Qb + ((size_t)(b*2048 + qb + qf*16 + lo))*256 + 8*hi;
  bf16x8 qfr[8];
#pragma unroll
  for (int kc=0;kc<8;kc++) qfr[kc] = *reinterpret_cast<const bf16x8*>(Qp + kc*32);

  const f32x4 fzero = {0.f,0.f,0.f,0.f};
  f32x4 accO[2][4];
#pragma unroll
  for (int i=0;i<2;i++)
#pragma unroll
    for (int j=0;j<4;j++) accO[i][j] = fzero;
  float m_run = NEGF, l_run = 0.f;

  auto stage = [&](int u, int buf){
    const char* gk = Kbb + (size_t)u*32*512;
    char* lk = (char*)Kt[buf];
#pragma unroll
    for (int c=0;c<4;c++){
      const int off = c*4096 + t*16;
      __builtin_amdgcn_global_load_lds(
        (const __attribute__((address_space(1))) unsigned int*)(gk + off),
        (__attribute__((address_space(3))) unsigned int*)(lk + off), 16, 0, 0);
    }
    char* lv = (char*)Vts[buf];
    const size_t kvb = (size_t)u*64;
#pragma unroll
    for (int c=0;c<4;c++){
      const int off = c*4096 + t*16;
      const int d = off >> 6, soff = off & 63;
      __builtin_amdgcn_global_load_lds(
        (const __attribute__((address_space(1))) unsigned int*)(Vtb + (size_t)d*4096 + kvb + soff),
        (__attribute__((address_space(3))) unsigned int*)(lv + off), 16, 0, 0);
    }
  };

  stage(u0, 0);
  asm volatile("s_waitcnt vmcnt(0)" ::: "memory");
  __syncthreads();

  for (int u = u0; u < u1; ++u){
    const int bb = (u - u0) & 1;
    // ---- QK quadrant ----
    f32x4 sv = fzero;
    const char* kt = (const char*)Kt[bb];
#pragma unroll
    for (int kc=0;kc<8;kc++){
      const int r = ks*16 + lo;
      bf16x8 kf = *reinterpret_cast<const bf16x8*>(
          kt + r*512 + (((kc*4 + hi) ^ (r&7))<<4));
      sv = __builtin_amdgcn_mfma_f32_16x16x32_bf16(qfr[kc], kf, sv, 0,0,0);
    }
#pragma unroll
    for (int r=0;r<4;r++){
      const int row = qf*16 + hi*4 + r;
      const int ch  = (ks*4 + (lo>>2)) ^ (row & 7);
      Sl[row*36 + ch*4 + (lo&3)] = sv[r];
    }
    __syncthreads();                                    // B1: S ready

    if (u + 1 < u1) stage(u+1, bb^1);

    // ---- softmax: lane reduces row srow, logical cols c8*4..+3 ----
    f32x4 s4 = *reinterpret_cast<const f32x4*>(&Sl[srow*36 + ((c8 ^ (srow&7))<<2)]);
    if (u == tile){
#pragma unroll
      for (int j=0;j<4;j++) if (c8*4 + j > srow) s4[j] = NEGF;
    }
    float mx = fmaxf(fmaxf(s4[0], s4[1]), fmaxf(s4[2], s4[3]));
#pragma unroll
    for (int sh=1; sh<8; sh<<=1) mx = fmaxf(mx, __shfl_xor(mx, sh, 64));
    const float mn = fmaxf(m_run, mx);
    const float alpha = __expf(m_run - mn);
    float p0 = __expf(s4[0]-mn), p1 = __expf(s4[1]-mn);
    float p2 = __expf(s4[2]-mn), p3 = __expf(s4[3]-mn);
    m_run = mn;
    float ps = (p0+p1) + (p2+p3);
#pragma unroll
    for (int sh=1; sh<8; sh<<=1) ps += __shfl_xor(ps, sh, 64);
    l_run = l_run*alpha + ps;
    if (c8 == 0) Al[srow] = alpha;
    uint2 pw; pw.x = pk2(p0,p1); pw.y = pk2(p2,p3);
    *reinterpret_cast<uint2*>((char*)Pl2 + srow*80 + c8*8) = pw;
    __syncthreads();                                    // B2: P, Al ready

    // ---- PV d-slice ----
    float al[2][4];
#pragma unroll
    for (int q2=0;q2<2;q2++)
#pragma unroll
      for (int r=0;r<4;r++) al[q2][r] = Al[q2*16 + hi*4 + r];
#pragma unroll
    for (int q2=0;q2<2;q2++)
#pragma unroll
      for (int nf=0;nf<4;nf++)
#pragma unroll
        for (int r=0;r<4;r++) accO[q2][nf][r] *= al[q2][r];

    bf16x8 paf[2];
#pragma unroll
    for (int q2=0;q2<2;q2++)
      paf[q2] = *reinterpret_cast<const bf16x8*>((char*)Pl2 + (q2*16+lo)*80 + hi*16);
    const char* vt = (const char*)Vts[bb];
#pragma unroll
    for (int nf=0;nf<4;nf++){
      const int d = w*64 + nf*16 + lo;
      bf16x8 vf = *reinterpret_cast<const bf16x8*>(vt + d*64 + hi*16);
#pragma unroll
      for (int q2=0;q2<2;q2++)
        accO[q2][nf] = __builtin_amdgcn_mfma_f32_16x16x32_bf16(paf[q2], vf, accO[q2][nf], 0,0,0);
    }
    asm volatile("s_waitcnt vmcnt(0)" ::: "memory");
    __syncthreads();                                    // B3: buffers reusable
  }

  if (c8 == 0){
    if (mode){ ML[(size_t)pidx*64 + srow*2] = m_run; ML[(size_t)pidx*64 + srow*2 + 1] = l_run; }
    else Ll[srow] = l_run;
  }
  __syncthreads();

  float* dst = (mode <= 1)
    ? (Out + ((size_t)(b*2048 + qb))*256 + w*64)
    : (P1 + ((size_t)(b*32 + (tile-32))*32)*256 + w*64);
#pragma unroll
  for (int q2=0;q2<2;q2++){
#pragma unroll
    for (int r=0;r<4;r++){
      const int q = q2*16 + hi*4 + r;
      const float fin = (mode == 0) ? 1.0f/(Ll[q] + 1e-9f) : 1.0f;
#pragma unroll
      for (int nf=0;nf<4;nf++)
        dst[(size_t)q*256 + nf*16 + lo] = accO[q2][nf][r]*fin;
    }
  }
}

// ---------------------------------------------------------------------------
// Kernel 3: flash combine for split tiles (32..63). Exact f32 merge.
// ---------------------------------------------------------------------------
__global__ void combine_kernel(float* __restrict__ Out, const float* __restrict__ P1,
                               const float* __restrict__ ML)
{
  const int bid = blockIdx.x;                 // 256 = 8 b x 32 tiles
  const int b = bid >> 5, tt = bid & 31;
  const int t = threadIdx.x;
  const int row = t >> 3, cb = (t & 7)*32;
  const size_t mlb = (size_t)((b*32 + tt)*2)*64 + row*2;
  const float m0 = ML[mlb],      l0 = ML[mlb + 1];
  const float m1 = ML[mlb + 64], l1 = ML[mlb + 65];
  const float M = fmaxf(m0, m1);
  const float sc0 = __expf(m0 - M), sc1 = __expf(m1 - M);
  const float inv = 1.0f/(sc0*l0 + sc1*l1 + 1e-9f);
  float* O = Out + ((size_t)(b*2048 + (32 + tt)*32 + row))*256 + cb;
  const float* P = P1 + ((size_t)(b*32 + tt)*32 + row)*256 + cb;
#pragma unroll
  for (int c=0;c<8;c++){
    float4 p0 = *reinterpret_cast<const float4*>(O + c*4);
    float4 p1 = *reinterpret_cast<const float4*>(P + c*4);
    float4 o;
    o.x = (sc0*p0.x + sc1*p1.x)*inv;
    o.y = (sc0*p0.y + sc1*p1.y)*inv;
    o.z = (sc0*p0.z + sc1*p1.z)*inv;
    o.w = (sc0*p0.w + sc1*p1.w)*inv;
    *reinterpret_cast<float4*>(O + c*4) = o;
  }
}

// ---------------------------------------------------------------------------
extern "C" void kernel_launch(void* const* d_in, const int* in_sizes, int n_in,
                              void* d_out, int out_size, void* d_ws, size_t ws_size,
                              hipStream_t stream)
{
  const float* E  = (const float*)d_in[0];
  const float* WQ = (const float*)d_in[1];
  const float* WK = (const float*)d_in[2];
  const float* WV = (const float*)d_in[3];
  const size_t elems = (size_t)8*2048*256;

  unsigned short* Qb = (unsigned short*)d_ws;
  unsigned short* Kb = Qb + elems;
  unsigned short* Vt = Kb + elems;
  unsigned short* Wb = Vt + elems;                       // 3*65536 ushorts
  float* P1 = (float*)((char*)d_ws + 3*elems*2 + 393216);
  float* ML = P1 + (size_t)8*32*32*256;

  const size_t NEED_MIN  = 3*elems*2 + 393216;           // QKV + Wb = 25.56MB
  const size_t NEED_FULL = NEED_MIN + ((size_t)8*32*32*256 + 32768)*4; // +8.5MB
  if (ws_size < NEED_MIN) return;
  const int split = (ws_size >= NEED_FULL) ? 1 : 0;

  wconv_kernel<<<dim3(3,8), 256, 0, stream>>>(WQ, WK, WV, Wb);
  qkv_proj_kernel<<<512, 256, 0, stream>>>(E, Wb, Qb, Kb, Vt);
  attn_kernel<<<split ? 768 : 512, 256, 0, stream>>>(Qb, Kb, Vt, (float*)d_out, split, P1, ML);
  if (split) combine_kernel<<<256, 256, 0, stream>>>((float*)d_out, P1, ML);
}

// Round 5
// 101.286 us; speedup vs baseline: 3.0176x; 1.0818x over previous
//
#include <hip/hip_runtime.h>
#include <stdint.h>

// ---------------------------------------------------------------------------
// SelfAttention: QKV proj (fp32 -> bf16 MFMA GEMM) + causal flash attention.
// B=8, S=2048, D=256. out fp32 [B,S,D].
//
// ws: Qb bf16 [B][S][D] linear (pre-scaled 1/16)
//     Ka bf16 fragment layout [B][u:64][c:16][l:64][j:8]
//          = K[kv=32u+(l&31)][d=16c+8*(l>>5)+j]      (QK A-operand, LDS-linear)
//     Vf bf16 fragment layout [B][u:64][c:2][dt:8][l:64][j:8]
//          = V[kv=32u+16c+8*(j>>2)+4*(l>>5)+(j&3)][d=32dt+(l&31)]
//            (PV A-operand with kv-permutation baked in; perfectly coalesced)
//     Wb bf16 pre-swizzled weights, P1 f32 split partials, ML f32 (m,l).
//
// Round 5 attn: 32x32 swapped-operand MFMA structure:
//   S^T = mfma(K,Q)  -> lane owns q=lane&31, P-row in registers,
//   softmax fully in-register (tree + 1 shfl), defer-max THR=8,
//   O^T = mfma(V^T,P) -> per-lane scalar rescale/normalize,
//   K staged via global_load_lds (fragment-linear = conflict-free ds_read),
//   V fragments direct from L2 (coalesced 1KB), 1 barrier/unit,
//   LDS-transpose epilogue for coalesced O stores.
// ---------------------------------------------------------------------------

typedef __attribute__((ext_vector_type(8)))  short bf16x8;
typedef __attribute__((ext_vector_type(4)))  float f32x4;
typedef __attribute__((ext_vector_type(16))) float f32x16;

#define NEGF -3.0e38f
#define LDP  40

__device__ __forceinline__ unsigned short f2bf(float f){
  union { float f; unsigned u; } v; v.f = f;
  unsigned r = v.u + 0x7FFFu + ((v.u >> 16) & 1u);   // RNE
  return (unsigned short)(r >> 16);
}
__device__ __forceinline__ unsigned pk2(float a, float b){
  return (unsigned)f2bf(a) | ((unsigned)f2bf(b) << 16);
}

// ---------------------------------------------------------------------------
// Kernel 0: weight convert (B-tile staging format for proj), unchanged.
// ---------------------------------------------------------------------------
__global__ void wconv_kernel(const float* __restrict__ WQ, const float* __restrict__ WK,
                             const float* __restrict__ WV, unsigned short* __restrict__ Wb)
{
  const int widx = blockIdx.x, kk = blockIdx.y, n = threadIdx.x;
  const float* W = (widx==0) ? WQ : ((widx==1) ? WK : WV);
  unsigned short* dst = Wb + (size_t)widx*65536 + kk*8192 + n*32;
#pragma unroll
  for (int gp=0; gp<4; ++gp){
    const int g = gp ^ (n & 3);
    const float* src = W + (size_t)n*256 + kk*32 + g*8;
    float4 a = *reinterpret_cast<const float4*>(src);
    float4 c = *reinterpret_cast<const float4*>(src + 4);
    uint4 v; v.x = pk2(a.x,a.y); v.y = pk2(a.z,a.w); v.z = pk2(c.x,c.y); v.w = pk2(c.z,c.w);
    *reinterpret_cast<uint4*>(dst + gp*8) = v;
  }
}

// ---------------------------------------------------------------------------
// Kernel 1: QKV projection (structure unchanged from R4; K/V epilogues now
// write the attn fragment layouts Ka / Vf).
// ---------------------------------------------------------------------------
__global__ __launch_bounds__(256) void qkv_proj_kernel(
    const float* __restrict__ E, const unsigned short* __restrict__ Wb,
    unsigned short* __restrict__ Qb, unsigned short* __restrict__ Ka,
    unsigned short* __restrict__ Vf)
{
  __shared__ unsigned short As[32*256];
  __shared__ unsigned short Bs[2][8192];

  const int m0 = blockIdx.x * 32;
  const int b  = m0 >> 11;
  const int sb = m0 & 2047;
  const int t = threadIdx.x, lane = t & 63, w = t >> 6;
  const int hi = lane >> 4, lo = lane & 15;

  auto stageB = [&](int widx, int kk, int buf){
    const char* src = (const char*)Wb + widx*131072 + kk*16384;
    char* dst = (char*)Bs[buf];
#pragma unroll
    for (int c=0;c<4;c++){
      const int off = c*4096 + t*16;
      __builtin_amdgcn_global_load_lds(
        (const __attribute__((address_space(1))) unsigned int*)(src + off),
        (__attribute__((address_space(3))) unsigned int*)(dst + off), 16, 0, 0);
    }
  };

  stageB(0, 0, 0);
  {
    const int r = t >> 3, c0 = (t & 7) * 32;
    const float* ga = E + (size_t)(m0 + r)*256 + c0;
#pragma unroll
    for (int gg=0; gg<4; ++gg){
      float4 x = *reinterpret_cast<const float4*>(ga + gg*8);
      float4 y = *reinterpret_cast<const float4*>(ga + gg*8 + 4);
      uint4 v; v.x = pk2(x.x,x.y); v.y = pk2(x.z,x.w); v.z = pk2(y.x,y.y); v.w = pk2(y.z,y.w);
      const int g = (t & 7)*4 + gg;
      *reinterpret_cast<uint4*>((char*)As + r*512 + ((g ^ (r & 7)) << 4)) = v;
    }
  }
  __syncthreads();

  const f32x4 fzero = {0.f,0.f,0.f,0.f};
  const int u = sb >> 5;   // 32-row block -> single kv unit index
  for (int widx=0; widx<3; ++widx){
    f32x4 acc[2][4];
#pragma unroll
    for (int mi=0;mi<2;mi++)
#pragma unroll
      for (int f=0;f<4;f++) acc[mi][f] = fzero;
    if (widx) stageB(widx, 0, 0);

    for (int kk=0; kk<8; ++kk){
      const int bb = kk & 1;
      asm volatile("s_waitcnt vmcnt(0)" ::: "memory");
      __syncthreads();
      if (kk < 7) stageB(widx, kk+1, bb^1);

      bf16x8 afr[2], bfr[4];
#pragma unroll
      for (int mi=0;mi<2;mi++){
        const int r = mi*16 + lo;
        afr[mi] = *reinterpret_cast<const bf16x8*>(
            (const char*)As + r*512 + (((kk*4 + hi) ^ (r & 7)) << 4));
      }
#pragma unroll
      for (int f=0;f<4;f++){
        const int n = w*64 + f*16 + lo;
        bfr[f] = *reinterpret_cast<const bf16x8*>(
            (const char*)Bs[bb] + n*64 + ((hi ^ (n & 3)) << 4));
      }
#pragma unroll
      for (int mi=0;mi<2;mi++)
#pragma unroll
        for (int f=0;f<4;f++)
          acc[mi][f] = __builtin_amdgcn_mfma_f32_16x16x32_bf16(afr[mi], bfr[f], acc[mi][f], 0,0,0);
    }

    // ---- epilogues (C/D: row = mi*16+hi*4+r, col = w*64+f*16+lo) ----
    if (widx == 0){
#pragma unroll
      for (int mi=0;mi<2;mi++)
#pragma unroll
        for (int f=0;f<4;f++){
          const int col = w*64 + f*16 + lo;
#pragma unroll
          for (int r=0;r<4;r++)
            Qb[(size_t)(m0 + mi*16 + hi*4 + r)*256 + col] = f2bf(acc[mi][f][r]*0.0625f);
        }
    } else if (widx == 1){
      // Ka fragment layout: [(u*16 + c)*64 + l]*8 + j
      unsigned short* Kab = Ka + (size_t)b*524288 + (size_t)u*8192;
#pragma unroll
      for (int mi=0;mi<2;mi++)
#pragma unroll
        for (int f=0;f<4;f++){
          const int c = w*4 + f;
          const int j = lo & 7;
          const int lb = 32*(lo>>3) + mi*16 + hi*4;
#pragma unroll
          for (int r=0;r<4;r++)
            Kab[(size_t)(c*64 + lb + r)*8 + j] = f2bf(acc[mi][f][r]);
        }
    } else {
      // Vf fragment layout (kv-permuted PV A-operand)
      unsigned short* Vfb = Vf + (size_t)b*524288;
#pragma unroll
      for (int mi=0;mi<2;mi++)
#pragma unroll
        for (int f=0;f<4;f++){
          const int d  = w*64 + f*16 + lo;
          const int dt = d >> 5;
          const int l  = 32*(hi&1) + (d&31);
          const int j0 = 4*(hi>>1);
          unsigned short* vp = Vfb + ((size_t)((u*2 + mi)*8 + dt)*64 + l)*8 + j0;
          uint2 pw; pw.x = pk2(acc[mi][f][0], acc[mi][f][1]);
          pw.y = pk2(acc[mi][f][2], acc[mi][f][3]);
          *reinterpret_cast<uint2*>(vp) = pw;
        }
    }
  }
}

// ---------------------------------------------------------------------------
// Kernel 2: causal flash attention, swapped-operand 32x32 structure.
// Block = 4 waves: wave (qs = w>>1) owns 32 q rows, (dh = w&1) owns 128 d.
// 384 blocks (split): cidx<32 -> tiles 31..16 in 2 kv-chunks (modes 1/2),
//                     cidx>=32 -> tiles 15..0 whole (mode 0).
// ---------------------------------------------------------------------------
__global__ __launch_bounds__(256, 2) void attn_kernel(
    const unsigned short* __restrict__ Qb, const unsigned short* __restrict__ Ka,
    const unsigned short* __restrict__ Vf, float* __restrict__ Out,
    const int split, float* __restrict__ P1, float* __restrict__ ML)
{
  __shared__ char Kt[2][16384];     // K unit tile, fragment-linear; reused as T

  const int bid  = blockIdx.x;
  const int b    = bid & 7;                   // batch == XCD
  const int cidx = bid >> 3;
  int tau, chunk, mode, u0, u1;
  if (split){
    if (cidx < 32){
      tau = 31 - (cidx >> 1); chunk = cidx & 1;
      u0 = chunk ? (tau + 1) : 0;
      u1 = chunk ? (2*tau + 2) : (tau + 1);
      mode = 1 + chunk;
    } else { tau = 47 - cidx; chunk = 0; u0 = 0; u1 = 2*tau + 2; mode = 0; }
  } else { tau = 31 - cidx; chunk = 0; u0 = 0; u1 = 2*tau + 2; mode = 0; }
  const int Qbase = tau * 64;

  const int t = threadIdx.x;
  const int lane = t & 63, w = t >> 6;
  const int qs = w >> 1, dh = w & 1;
  const int l31 = lane & 31, h5 = lane >> 5;
  const int q_l = Qbase + qs*32 + l31;        // this lane's q row (softmax view)
  const int diagu = 2*tau + qs;               // first unit needing a mask

  const char* Kab = (const char*)Ka + (size_t)b*1048576;
  const char* Vfb = (const char*)Vf + (size_t)b*1048576;

  auto stage = [&](int uu){
    const char* src = Kab + (size_t)uu*16384;
    char* dstl = (char*)Kt[uu & 1];
#pragma unroll
    for (int i=0;i<4;i++){
      const int off = i*4096 + t*16;
      __builtin_amdgcn_global_load_lds(
        (const __attribute__((address_space(1))) unsigned int*)(src + off),
        (__attribute__((address_space(3))) unsigned int*)(dstl + off), 16, 0, 0);
    }
  };

  // Q fragments (QK B-operand): Q[q = Qbase+qs*32+l31][d = 16c + 8*h5 + j]
  bf16x8 qf[16];
  {
    const unsigned short* Qp = Qb + ((size_t)(b*2048 + q_l))*256 + h5*8;
#pragma unroll
    for (int c=0;c<16;c++) qf[c] = *reinterpret_cast<const bf16x8*>(Qp + c*16);
  }

  const f32x16 z16 = {0.f,0.f,0.f,0.f,0.f,0.f,0.f,0.f,0.f,0.f,0.f,0.f,0.f,0.f,0.f,0.f};
  f32x16 accO[4];
#pragma unroll
  for (int i=0;i<4;i++) accO[i] = z16;
  float m_run = NEGF, l_run = 0.f;

  stage(u0);

  for (int u = u0; u < u1; ++u){
    asm volatile("s_waitcnt vmcnt(0)" ::: "memory");   // stage(u) landed
    __builtin_amdgcn_s_barrier();
    if (u + 1 < u1) stage(u+1);                         // into other buffer

    // V fragments for this unit (direct from L2, coalesced 1KB each)
    const char* Vu = Vfb + (size_t)u*16384 + dh*4096 + lane*16;
    bf16x8 vf0[4], vf1[4];
#pragma unroll
    for (int i=0;i<4;i++){
      vf0[i] = *reinterpret_cast<const bf16x8*>(Vu + i*1024);
      vf1[i] = *reinterpret_cast<const bf16x8*>(Vu + 8192 + i*1024);
    }

    // ---- QK^T swapped: S^T[kv][q] = sum_c mfma(K[c], Q[c]) ----
    const char* kt = Kt[u & 1];
    f32x16 sv0 = z16, sv1 = z16;
#pragma unroll
    for (int c=0;c<16;c+=2){
      bf16x8 a0 = *reinterpret_cast<const bf16x8*>(kt + c*1024 + lane*16);
      bf16x8 a1 = *reinterpret_cast<const bf16x8*>(kt + (c+1)*1024 + lane*16);
      sv0 = __builtin_amdgcn_mfma_f32_32x32x16_bf16(a0, qf[c],   sv0, 0,0,0);
      sv1 = __builtin_amdgcn_mfma_f32_32x32x16_bf16(a1, qf[c+1], sv1, 0,0,0);
    }
    f32x16 s16 = sv0 + sv1;

    // ---- causal mask (lane holds kv = u*32 + (r&3)+8*(r>>2)+4*h5, q=l31) ----
    if (u >= diagu){
      const int kvb = u*32 + 4*h5;
#pragma unroll
      for (int r=0;r<16;r++){
        const int kv = kvb + (r&3) + 8*(r>>2);
        if (kv > q_l) s16[r] = NEGF;
      }
    }

    // ---- in-register softmax ----
    float t8[8], t4[4];
#pragma unroll
    for (int i=0;i<8;i++) t8[i] = fmaxf(s16[i], s16[i+8]);
#pragma unroll
    for (int i=0;i<4;i++) t4[i] = fmaxf(t8[i], t8[i+4]);
    float pmax = fmaxf(fmaxf(t4[0],t4[1]), fmaxf(t4[2],t4[3]));
    pmax = fmaxf(pmax, __shfl_xor(pmax, 32, 64));

    if (!__all(pmax - m_run <= 8.0f)){        // defer-max THR=8
      const float mn = fmaxf(m_run, pmax);
      const float alpha = __expf(m_run - mn);
#pragma unroll
      for (int i=0;i<4;i++) accO[i] *= alpha;
      l_run *= alpha;
      m_run = mn;
    }
    float p[16];
#pragma unroll
    for (int r=0;r<16;r++) p[r] = __expf(s16[r] - m_run);
#pragma unroll
    for (int i=0;i<8;i++) t8[i] = p[i] + p[i+8];
#pragma unroll
    for (int i=0;i<4;i++) t4[i] = t8[i] + t8[i+4];
    float ls = (t4[0]+t4[1]) + (t4[2]+t4[3]);
    ls += __shfl_xor(ls, 32, 64);
    l_run += ls;

    // ---- pack P (kv-permutation matches Vf layout: pa_c = p[8c..8c+7]) ----
    union { bf16x8 v; unsigned u32[4]; } pa0, pa1;
#pragma unroll
    for (int k=0;k<4;k++){
      pa0.u32[k] = pk2(p[2*k],   p[2*k+1]);
      pa1.u32[k] = pk2(p[8+2*k], p[9+2*k]);
    }

    // ---- PV swapped: O^T[d][q] += mfma(V^T, P) ----
#pragma unroll
    for (int i=0;i<4;i++){
      accO[i] = __builtin_amdgcn_mfma_f32_32x32x16_bf16(vf0[i], pa0.v, accO[i], 0,0,0);
      accO[i] = __builtin_amdgcn_mfma_f32_32x32x16_bf16(vf1[i], pa1.v, accO[i], 0,0,0);
    }
  }

  // ---- write m,l for split partials (lane view q=l31; dh==0 only) ----
  if (mode && dh == 0 && lane < 32){
    float* mlp = ML + ((size_t)((b*16 + (tau-16))*2 + chunk)*64 + qs*32 + lane)*2;
    mlp[0] = m_run; mlp[1] = l_run;
  }

  __syncthreads();   // all waves done with Kt -> reuse as transpose scratch

  // ---- LDS-transpose epilogue: accO (O^T, col=q=l31) -> row-major O ----
  const float inv = (mode == 0) ? 1.0f/(l_run + 1e-9f) : 1.0f;
  float* Tw = (float*)(&Kt[0][0]) + w*2048;   // 8KB per wave
  const int qloc = lane >> 1, dc = (lane & 1) * 16;
#pragma unroll
  for (int i=0;i<4;i++){
#pragma unroll
    for (int r=0;r<16;r++)
      Tw[l31*33 + ((r&3) + 8*(r>>2) + 4*h5)] = accO[i][r] * inv;
    asm volatile("s_waitcnt lgkmcnt(0)" ::: "memory");
    __builtin_amdgcn_sched_barrier(0);
    float* dst = (mode <= 1)
      ? (Out + ((size_t)(b*2048 + Qbase + qs*32 + qloc))*256 + dh*128 + i*32 + dc)
      : (P1 + ((size_t)((b*16 + (tau-16))*64 + qs*32 + qloc))*256 + dh*128 + i*32 + dc);
#pragma unroll
    for (int k=0;k<4;k++){
      float4 vv = { Tw[qloc*33 + dc + 4*k],     Tw[qloc*33 + dc + 4*k + 1],
                    Tw[qloc*33 + dc + 4*k + 2], Tw[qloc*33 + dc + 4*k + 3] };
      *reinterpret_cast<float4*>(dst + 4*k) = vv;
    }
    asm volatile("s_waitcnt lgkmcnt(0)" ::: "memory");   // reads done before next overwrite
    __builtin_amdgcn_sched_barrier(0);
  }
}

// ---------------------------------------------------------------------------
// Kernel 3: flash combine for split tiles (16..31). Exact f32 merge.
// ---------------------------------------------------------------------------
__global__ void combine_kernel(float* __restrict__ Out, const float* __restrict__ P1,
                               const float* __restrict__ ML)
{
  const int bid = blockIdx.x;                 // 128 = 8 b x 16 tiles
  const int b = bid >> 4, tt = bid & 15;
  const int t = threadIdx.x;
  const int q = t >> 2, dg = (t & 3) * 64;
  const size_t mlb = ((size_t)(b*16 + tt)*2)*64 + q;
  const float m0 = ML[mlb*2],          l0 = ML[mlb*2 + 1];
  const float m1 = ML[(mlb + 64)*2],   l1 = ML[(mlb + 64)*2 + 1];
  const float M = fmaxf(m0, m1);
  const float e0 = __expf(m0 - M), e1 = __expf(m1 - M);
  const float inv = 1.0f/(e0*l0 + e1*l1 + 1e-9f);
  float* O = Out + ((size_t)(b*2048 + (16 + tt)*64 + q))*256 + dg;
  const float* P = P1 + ((size_t)((b*16 + tt)*64 + q))*256 + dg;
#pragma unroll
  for (int k=0;k<16;k++){
    float4 a = *reinterpret_cast<const float4*>(O + k*4);
    float4 c = *reinterpret_cast<const float4*>(P + k*4);
    float4 o;
    o.x = (e0*a.x + e1*c.x)*inv; o.y = (e0*a.y + e1*c.y)*inv;
    o.z = (e0*a.z + e1*c.z)*inv; o.w = (e0*a.w + e1*c.w)*inv;
    *reinterpret_cast<float4*>(O + k*4) = o;
  }
}

// ---------------------------------------------------------------------------
extern "C" void kernel_launch(void* const* d_in, const int* in_sizes, int n_in,
                              void* d_out, int out_size, void* d_ws, size_t ws_size,
                              hipStream_t stream)
{
  const float* E  = (const float*)d_in[0];
  const float* WQ = (const float*)d_in[1];
  const float* WK = (const float*)d_in[2];
  const float* WV = (const float*)d_in[3];
  const size_t elems = (size_t)8*2048*256;

  unsigned short* Qb = (unsigned short*)d_ws;
  unsigned short* Ka = Qb + elems;
  unsigned short* Vf = Ka + elems;
  unsigned short* Wb = Vf + elems;                       // 3*65536 ushorts
  float* P1 = (float*)((char*)d_ws + 3*elems*2 + 393216);
  float* ML = P1 + (size_t)8*16*64*256;                  // 8MB partials, 128KB ml

  const size_t NEED_MIN  = 3*elems*2 + 393216;
  const size_t NEED_FULL = NEED_MIN + ((size_t)8*16*64*256 + 32768)*4;
  if (ws_size < NEED_MIN) return;
  const int split = (ws_size >= NEED_FULL) ? 1 : 0;

  wconv_kernel<<<dim3(3,8), 256, 0, stream>>>(WQ, WK, WV, Wb);
  qkv_proj_kernel<<<512, 256, 0, stream>>>(E, Wb, Qb, Ka, Vf);
  attn_kernel<<<split ? 384 : 256, 256, 0, stream>>>(Qb, Ka, Vf, (float*)d_out, split, P1, ML);
  if (split) combine_kernel<<<128, 256, 0, stream>>>((float*)d_out, P1, ML);
}